// Round 1
// baseline (204.864 us; speedup 1.0000x reference)
//
#include <hip/hip_runtime.h>
#include <hip/hip_bf16.h>

#define NFFT   4194304
#define NMODES 2
#define NTAPS  101
#define NVALID (NFFT - NTAPS + 1)   // 4194204
#define N0     (NTAPS / 2)          // 50

constexpr int BLOCK = 256;                          // 4 waves
constexpr int TILE  = 2048;                         // output samples per tile (512/wave)
constexpr int NT    = (NVALID + TILE - 1) / TILE;   // 2048 tiles
constexpr int GRID  = 1024;                         // grid-stride: 2 tiles/block, B-frags amortized
constexpr int WIN   = 2176;                         // staged P samples (max read idx 2151)
constexpr int NM    = 15;                           // banded MFMA accumulation steps

typedef __attribute__((ext_vector_type(8)))  short short8;
typedef __attribute__((ext_vector_type(16))) float float16;

static __device__ __forceinline__ unsigned short f2bf(float x) {
    __hip_bfloat16 h = __float2bfloat16(x);
    return *reinterpret_cast<unsigned short*>(&h);
}
static __device__ __forceinline__ unsigned pk(float e0, float e1) {
    return (unsigned)f2bf(e0) | ((unsigned)f2bf(e1) << 16);
}
// LDS bank swizzle: permute word bits 2..4 by sample bits 5..7 (keeps uint4 alignment,
// spreads the 64B row stride of the A-fragment reads across banks; residual 2-way = free)
static __device__ __forceinline__ int swz(int s) {
    return s ^ (((s >> 5) & 7) << 2);
}

__global__ __launch_bounds__(BLOCK, 3) void nl_kernel(
    const float* __restrict__ xa,   // d_in[0] big stream (A = xr)
    const float* __restrict__ xb,   // d_in[1] big stream (B = xi)
    const float* __restrict__ W,  const float* __restrict__ b,
    const float* __restrict__ power, unsigned* __restrict__ out)
{
    // P sample S (bf16x2 packed in one uint: mode0 low, mode1 high) at word swz(S)
    __shared__ __align__(16) unsigned Pl[WIN];

    const int tid  = threadIdx.x;
    const int lane = tid & 63;
    const int wid  = tid >> 6;
    const int colc = lane & 31;      // B/C column = (c_s<<1)|o ; also A row index
    const int h    = lane >> 5;      // k half: k = 8h + e
    const int cs   = colc >> 1;      // fine shift 0..15
    const int o    = colc & 1;       // output mode
    const int r    = colc;           // A row (lane&31)

    // ---- B fragments: B_m[k=(dt,i)][c=(cs,o)] = W[8m + dt - cs, i, o], banded ----
    // lane (c,h) elem e: dt = 4h + (e>>1), i = e&1. Built once per block (grid-stride).
    short8 Bf[NM];
    const float4* __restrict__ Wt = reinterpret_cast<const float4*>(W); // W[t] = {i0o0,i0o1,i1o0,i1o1}
    #pragma unroll
    for (int m = 0; m < NM; ++m) {
        short8 bb;
        #pragma unroll
        for (int d = 0; d < 4; ++d) {
            const int t  = 8 * m + 4 * h + d - cs;
            const bool ok = (unsigned)t <= 100u;
            const float4 w = Wt[ok ? t : 0];
            const float v0 = ok ? (o ? w.y : w.x) : 0.f;   // W[t][i=0][o]
            const float v1 = ok ? (o ? w.w : w.z) : 0.f;   // W[t][i=1][o]
            bb[2 * d]     = (short)f2bf(v0);
            bb[2 * d + 1] = (short)f2bf(v1);
        }
        Bf[m] = bb;
    }

    const float bo   = o ? b[1] : b[0];
    const float coef = 0.066268f * exp10f(power[0] * 0.1f);

    const float4* __restrict__ xa4 = reinterpret_cast<const float4*>(xa); // 2 samples
    const float4* __restrict__ xb4 = reinterpret_cast<const float4*>(xb);

    for (int tile = blockIdx.x; tile < NT; tile += GRID) {
        const int tile_start = tile * TILE;
        if (tile != (int)blockIdx.x) __syncthreads();   // LDS reuse guard

        // ---- stage P = xa^2 + xb^2 as bf16x2, swizzled; loads hoisted for MLP ----
        float4 sa[5], sc[5];
        #pragma unroll
        for (int k = 0; k < 5; ++k) {
            const int s = 2 * tid + 512 * k;
            const int g = tile_start + s;
            const bool v = (k < 4 || s < WIN) && (g < NFFT);
            sa[k] = v ? xa4[g >> 1] : make_float4(0.f, 0.f, 0.f, 0.f);
            sc[k] = v ? xb4[g >> 1] : make_float4(0.f, 0.f, 0.f, 0.f);
        }
        #pragma unroll
        for (int k = 0; k < 5; ++k) {
            const int s = 2 * tid + 512 * k;
            if (k < 4 || s < WIN) {
                const float4 a = sa[k], c = sc[k];
                const unsigned u0 = pk(a.x * a.x + c.x * c.x, a.y * a.y + c.y * c.y);
                const unsigned u1 = pk(a.z * a.z + c.z * c.z, a.w * a.w + c.w * c.w);
                *reinterpret_cast<uint2*>(&Pl[swz(s)]) = make_uint2(u0, u1);
            }
        }
        __syncthreads();

        // ---- per-wave 512-sample chunk: 15 x (aligned ds_read_b128 + 32x32x16 MFMA) ----
        // A_m[r][k=(dt,i)] = P[cb + 16r + 8m + dt, i]; lane (r,h) reads samples
        // cb + 16r + 8m + 4h + 0..3 as one 16B-aligned uint4 (bf16x8, k-order matches).
        const int cb = wid * 512;
        float16 acc = {};                 // fp32 accumulators (zero)
        uint4 areg[4];                    // 4-deep A prefetch pipe (static idx post-unroll)
        #pragma unroll
        for (int m = 0; m < 4; ++m)
            areg[m] = *reinterpret_cast<const uint4*>(&Pl[swz(cb + 16 * r + 8 * m + 4 * h)]);
        #pragma unroll
        for (int m = 0; m < NM; ++m) {
            acc = __builtin_amdgcn_mfma_f32_32x32x16_bf16(
                      __builtin_bit_cast(short8, areg[m & 3]), Bf[m], acc, 0, 0, 0);
            if (m + 4 < NM)
                areg[m & 3] = *reinterpret_cast<const uint4*>(
                                  &Pl[swz(cb + 16 * r + 8 * (m + 4) + 4 * h)]);
        }

        // ---- epilogue: phi -> rotate -> bf16 pack (verified R7 form) ----
        // C/D layout: col = lane&31, row = (reg&3) + 8*(reg>>2) + 4*(lane>>5)
        // sample n = tile_start + cb + 16*row + cs, mode o. Per store instruction the
        // wave covers two full 128B segments (32*row + c contiguous in c) -> coalesced.
        #pragma unroll
        for (int j = 0; j < 16; ++j) {
            const int row = (j & 3) + 8 * (j >> 2) + 4 * h;
            const int n   = tile_start + cb + 16 * row + cs;
            if (n < NVALID) {
                const float Ax = xa[(n + N0) * 2 + o];
                const float Bx = xb[(n + N0) * 2 + o];
                float sn, cn;
                __sincosf((acc[j] + bo) * coef, &sn, &cn);
                out[n * 2 + o] = pk(Bx * cn - Ax * sn, Ax * cn + Bx * sn);
            }
        }
    }
}

extern "C" void kernel_launch(void* const* d_in, const int* in_sizes, int n_in,
                              void* d_out, int out_size, void* d_ws, size_t ws_size,
                              hipStream_t stream) {
    // Bind by size (robust): big arrays = x streams, 404 = W, 2 = b, 1 = power.
    const float* big[2] = {nullptr, nullptr};
    const float* W = nullptr; const float* b = nullptr; const float* power = nullptr;
    int nbig = 0;
    for (int i = 0; i < n_in; ++i) {
        const float* p = (const float*)d_in[i];
        const int sz = in_sizes[i];
        if (sz == NFFT * NMODES)       { if (nbig < 2) big[nbig++] = p; }
        else if (sz == NTAPS * NMODES * NMODES) { W = p; }
        else if (sz == NMODES)         { b = p; }
        else if (sz == 1)              { power = p; }
    }

    unsigned* out = (unsigned*)d_out;
    nl_kernel<<<GRID, BLOCK, 0, stream>>>(big[0], big[1], W, b, power, out);
}